// Round 4
// baseline (198.831 us; speedup 1.0000x reference)
//
#include <hip/hip_runtime.h>
#include <hip/hip_bf16.h>
#include <math.h>

#define N_TOT 1024
#define C_DIM 4096

typedef __attribute__((ext_vector_type(8))) short short8;
typedef __attribute__((ext_vector_type(8))) unsigned short ushort8;
typedef __attribute__((ext_vector_type(4))) float floatx4;

__device__ inline unsigned short bf16_rn(float v) {
    unsigned int u = __float_as_uint(v);
    unsigned int r = (u + 0x7FFFu + ((u >> 16) & 1u)) >> 16;
    return (unsigned short)r;
}
__device__ inline float bf2f(unsigned short h) {
    return __uint_as_float(((unsigned int)h) << 16);
}

// ---------------------------------------------------------------------------
// split+transpose+norms: X (C,N) fp32 -> Xhi[n][c], Xlo[n][c] bf16, and
// normX[n] += sum_c x^2 (atomic, pre-zeroed). grid (64, 16, 2). ushort4 stores.
__global__ __launch_bounds__(256) void split_norms(const float* __restrict__ G,
                                                   const float* __restrict__ Kn,
                                                   unsigned short* __restrict__ Phi,
                                                   unsigned short* __restrict__ Plo,
                                                   unsigned short* __restrict__ Khi,
                                                   unsigned short* __restrict__ Klo,
                                                   float* __restrict__ normP,
                                                   float* __restrict__ normK) {
    const int z = blockIdx.z;
    const float* X = z ? Kn : G;
    unsigned short* Xhi = z ? Khi : Phi;
    unsigned short* Xlo = z ? Klo : Plo;
    float* normX = z ? normK : normP;

    __shared__ float tile[64 * 65];
    __shared__ float np[256];
    const int t  = threadIdx.x;
    const int c0 = blockIdx.x * 64;
    const int n0 = blockIdx.y * 64;

    float s2 = 0.0f;
    #pragma unroll
    for (int s = 0; s < 16; s++) {
        int c_loc = s * 4 + (t >> 6);
        int n_loc = t & 63;
        float v = X[(c0 + c_loc) * N_TOT + n0 + n_loc];
        tile[c_loc * 65 + n_loc] = v;
        s2 = fmaf(v, v, s2);
    }
    np[t] = s2;
    __syncthreads();

    if (t < 64) {
        float tot = np[t] + np[t + 64] + np[t + 128] + np[t + 192];
        atomicAdd(&normX[n0 + t], tot);
    }

    #pragma unroll
    for (int s = 0; s < 4; s++) {
        int n_loc = s * 16 + (t >> 4);
        int c4    = (t & 15) * 4;
        unsigned short h[4], l[4];
        #pragma unroll
        for (int e = 0; e < 4; e++) {
            float v = tile[(c4 + e) * 65 + n_loc];
            h[e] = bf16_rn(v);
            l[e] = bf16_rn(v - bf2f(h[e]));
        }
        size_t base = (size_t)(n0 + n_loc) * C_DIM + c0 + c4;
        *(ushort4*)&Xhi[base] = make_ushort4(h[0], h[1], h[2], h[3]);
        *(ushort4*)&Xlo[base] = make_ushort4(l[0], l[1], l[2], l[3]);
    }
}

// ---------------------------------------------------------------------------
// coarse hi-only MFMA GEMM: dot0 ~= P.K^T, dot1 ~= P.P^T (bf16 hi x hi).
// 64x64 tile, BK=64, 256 threads (4 waves of 32x32), K-split 4 -> grid
// (16,16,4) = 1024 blocks = 4/CU, LDS 24 KB. atomicAdd into zeroed buffers.
// Coarse cosine error ~3e-5 — used only to select top-8 candidates per row.
__global__ __launch_bounds__(256, 4) void gemm_coarse(const unsigned short* __restrict__ Phi,
                                                      const unsigned short* __restrict__ Khi,
                                                      float* __restrict__ dot0,
                                                      float* __restrict__ dot1) {
    __shared__ unsigned short sAh[64 * 64];
    __shared__ unsigned short sKh[64 * 64];
    __shared__ unsigned short sPh[64 * 64];

    const int t    = threadIdx.x;
    const int wave = t >> 6, lane = t & 63;
    const int wm   = wave >> 1, wn = wave & 1;
    const int quad = lane >> 4, lrow = lane & 15;
    const int ib = blockIdx.x * 64, jb = blockIdx.y * 64;
    const int k_beg = blockIdx.z * 1024;

    const int srow = t >> 3;            // 0..31
    const int g    = (t & 7) ^ (srow & 7);

    const unsigned short* gAh = Phi + (size_t)(ib + srow) * C_DIM + g * 8;
    const unsigned short* gKh = Khi + (size_t)(jb + srow) * C_DIM + g * 8;
    const unsigned short* gPh = Phi + (size_t)(jb + srow) * C_DIM + g * 8;
    const size_t rstep = (size_t)32 * C_DIM;

    floatx4 acc0[2][2] = {};
    floatx4 acc1[2][2] = {};

    for (int k0 = k_beg; k0 < k_beg + 1024; k0 += 64) {
        #pragma unroll
        for (int q = 0; q < 2; q++) {
            int lds_off = q * 4096 + t * 16;   // bytes
            #define STAGE(SPTR, GPTR) \
                __builtin_amdgcn_global_load_lds( \
                    (const __attribute__((address_space(1))) void*)((GPTR) + q * rstep + k0), \
                    (__attribute__((address_space(3))) void*)((char*)(SPTR) + lds_off), 16, 0, 0)
            STAGE(sAh, gAh); STAGE(sKh, gKh); STAGE(sPh, gPh);
            #undef STAGE
        }
        __syncthreads();

        #pragma unroll
        for (int kk = 0; kk < 2; kk++) {
            short8 a_h[2], bk_h[2], bp_h[2];
            #pragma unroll
            for (int ti = 0; ti < 2; ti++) {
                int m  = wm * 32 + ti * 16 + lrow;
                int gk = kk * 4 + quad;
                int off = m * 64 + ((gk ^ (m & 7)) << 3);
                a_h[ti] = *(const short8*)&sAh[off];
            }
            #pragma unroll
            for (int tj = 0; tj < 2; tj++) {
                int n  = wn * 32 + tj * 16 + lrow;
                int gk = kk * 4 + quad;
                int off = n * 64 + ((gk ^ (n & 7)) << 3);
                bk_h[tj] = *(const short8*)&sKh[off];
                bp_h[tj] = *(const short8*)&sPh[off];
            }
            #pragma unroll
            for (int ti = 0; ti < 2; ti++)
                #pragma unroll
                for (int tj = 0; tj < 2; tj++) {
                    acc0[ti][tj] = __builtin_amdgcn_mfma_f32_16x16x32_bf16(a_h[ti], bk_h[tj], acc0[ti][tj], 0, 0, 0);
                    acc1[ti][tj] = __builtin_amdgcn_mfma_f32_16x16x32_bf16(a_h[ti], bp_h[tj], acc1[ti][tj], 0, 0, 0);
                }
        }
        __syncthreads();
    }

    // C/D layout: col=lane&15, row=quad*4+reg
    #pragma unroll
    for (int tj = 0; tj < 2; tj++) {
        int j = jb + wn * 32 + tj * 16 + lrow;
        #pragma unroll
        for (int ti = 0; ti < 2; ti++) {
            #pragma unroll
            for (int reg = 0; reg < 4; reg++) {
                int i = ib + wm * 32 + ti * 16 + quad * 4 + reg;
                atomicAdd(&dot0[i * N_TOT + j], acc0[ti][tj][reg]);
                atomicAdd(&dot1[i * N_TOT + j], acc1[ti][tj][reg]);
            }
        }
    }
}

// ---------------------------------------------------------------------------
// coarse top-8 (iterative wave argmax, lex (v,-j)) then fp32 refinement of
// the 8 candidate dots from hi+lo planes; exact top-2 with tie-break.
// one wave per (row, matrix). grid (1024, 2), block 64.
__global__ __launch_bounds__(64) void topk_refine(const float* __restrict__ dot0,
                                                  const float* __restrict__ dot1,
                                                  const unsigned short* __restrict__ Phi,
                                                  const unsigned short* __restrict__ Plo,
                                                  const unsigned short* __restrict__ Khi,
                                                  const unsigned short* __restrict__ Klo,
                                                  const float* __restrict__ normP,
                                                  const float* __restrict__ normK,
                                                  const float* __restrict__ flag,
                                                  float* __restrict__ w01,   // [2][N][2]
                                                  int* __restrict__ i01) {   // [2][N][2]
    const int row = blockIdx.x;
    const int z   = blockIdx.y;
    const int lane = threadIdx.x;
    const float* D = z ? dot1 : dot0;
    const unsigned short* Bh = z ? Phi : Khi;
    const unsigned short* Bl = z ? Plo : Klo;
    const float target = z ? 1.0f : 0.0f;

    // coarse values (masked), 16 strided per lane
    float v[16];
    #pragma unroll
    for (int s = 0; s < 16; s++) {
        int j = s * 64 + lane;
        v[s] = (flag[j] == target) ? D[row * N_TOT + j] : -INFINITY;
    }

    int cand[8];
    #pragma unroll
    for (int q = 0; q < 8; q++) {
        float bv = -INFINITY; int bj = 0x7FFFFFFF;
        #pragma unroll
        for (int s = 0; s < 16; s++) {
            int j = s * 64 + lane;
            if (v[s] > bv || (v[s] == bv && j < bj)) { bv = v[s]; bj = j; }
        }
        #pragma unroll
        for (int off = 32; off > 0; off >>= 1) {
            float ov = __shfl_xor(bv, off);
            int   oj = __shfl_xor(bj, off);
            if (ov > bv || (ov == bv && oj < bj)) { bv = ov; bj = oj; }
        }
        cand[q] = bj;                       // uniform across wave
        if (lane == (bj & 63)) v[bj >> 6] = -INFINITY;   // exclude
    }

    // fp32 refinement of the 8 candidate dots
    const unsigned short* Ah = Phi + (size_t)row * C_DIM;
    const unsigned short* Al = Plo + (size_t)row * C_DIM;
    float acc[8] = {};
    for (int it = 0; it < 8; it++) {
        int cb = it * 512 + lane * 8;
        ushort8 ah = *(const ushort8*)&Ah[cb];
        ushort8 al = *(const ushort8*)&Al[cb];
        float a[8];
        #pragma unroll
        for (int e = 0; e < 8; e++) a[e] = bf2f(ah[e]) + bf2f(al[e]);
        #pragma unroll
        for (int q = 0; q < 8; q++) {
            const unsigned short* bh = Bh + (size_t)cand[q] * C_DIM + cb;
            const unsigned short* bl = Bl + (size_t)cand[q] * C_DIM + cb;
            ushort8 hb = *(const ushort8*)bh;
            ushort8 lb = *(const ushort8*)bl;
            #pragma unroll
            for (int e = 0; e < 8; e++)
                acc[q] = fmaf(a[e], bf2f(hb[e]) + bf2f(lb[e]), acc[q]);
        }
    }
    #pragma unroll
    for (int q = 0; q < 8; q++)
        #pragma unroll
        for (int off = 32; off > 0; off >>= 1)
            acc[q] += __shfl_xor(acc[q], off);

    if (lane == 0) {
        float nr = normP[row];
        const float* nB = z ? normP : normK;
        float v1 = -INFINITY, v2 = -INFINITY;
        int   j1 = 0x7FFFFFFF, j2 = 0x7FFFFFFF;
        #pragma unroll
        for (int q = 0; q < 8; q++) {
            int j = cand[q];
            float cv = acc[q] * rsqrtf(nr * nB[j]);
            if (cv > v1 || (cv == v1 && j < j1)) {
                v2 = v1; j2 = j1; v1 = cv; j1 = j;
            } else if (cv > v2 || (cv == v2 && j < j2)) {
                v2 = cv; j2 = j;
            }
        }
        int base = (z * N_TOT + row) * 2;
        w01[base]     = v1;
        w01[base + 1] = v2;
        i01[base]     = j1;
        i01[base + 1] = j2;
    }
}

// ---------------------------------------------------------------------------
// output: inline means->softmax->weights (per-block redundant, L2-hot), copy
// generated & known (float4), rtn = weighted gather. grid (4096), block 256.
__global__ __launch_bounds__(256) void output_kernel(const float* __restrict__ G,
                                                     const float* __restrict__ Kn,
                                                     const float* __restrict__ flag,
                                                     const float* __restrict__ w01,
                                                     const int* __restrict__ i01,
                                                     float* __restrict__ out) {
    __shared__ float red[5][4];
    __shared__ float wts[4];
    const int c  = blockIdx.x;
    const int t  = threadIdx.x;
    const int n4 = t * 4;

    float4 fv = *(const float4*)&flag[n4];
    const float fa[4] = {fv.x, fv.y, fv.z, fv.w};

    // means partials over this thread's 4 rows
    float pm[5] = {};
    #pragma unroll
    for (int e = 0; e < 4; e++) {
        int n = n4 + e;
        float m = fa[e];
        pm[0] += m;
        pm[1] += m * w01[n * 2 + 0];
        pm[2] += m * w01[n * 2 + 1];
        pm[3] += m * w01[2 * N_TOT + n * 2 + 0];
        pm[4] += m * w01[2 * N_TOT + n * 2 + 1];
    }
    #pragma unroll
    for (int i = 0; i < 5; i++)
        #pragma unroll
        for (int off = 32; off > 0; off >>= 1)
            pm[i] += __shfl_xor(pm[i], off);
    const int wave = t >> 6, lane = t & 63;
    if (lane == 0) {
        #pragma unroll
        for (int i = 0; i < 5; i++) red[i][wave] = pm[i];
    }
    __syncthreads();
    if (t == 0) {
        float tot[5];
        #pragma unroll
        for (int i = 0; i < 5; i++)
            tot[i] = red[i][0] + red[i][1] + red[i][2] + red[i][3];
        float inv = 1.0f / tot[0];
        float mv[4] = {tot[1] * inv, tot[2] * inv, tot[3] * inv, tot[4] * inv};
        float mx = fmaxf(fmaxf(mv[0], mv[1]), fmaxf(mv[2], mv[3]));
        float e[4], s = 0.0f;
        #pragma unroll
        for (int q = 0; q < 4; q++) { e[q] = expf(mv[q] - mx); s += e[q]; }
        #pragma unroll
        for (int q = 0; q < 4; q++) wts[q] = e[q] / s;
    }
    __syncthreads();
    const float w0 = wts[0], w1 = wts[1], w2 = wts[2], w3 = wts[3];

    float4 gv = *(const float4*)&G[c * N_TOT + n4];
    float4 kv = *(const float4*)&Kn[c * N_TOT + n4];
    *(float4*)&out[c * N_TOT + n4] = gv;
    *(float4*)&out[C_DIM * N_TOT + c * N_TOT + n4] = kv;

    float val[4];
    #pragma unroll
    for (int e = 0; e < 4; e++) {
        int n = n4 + e;
        float v = 0.0f;
        if (fa[e] == 1.0f) {
            int c00 = i01[n * 2 + 0];
            int c01 = i01[n * 2 + 1];
            int c10 = i01[2 * N_TOT + n * 2 + 0];
            int c11 = i01[2 * N_TOT + n * 2 + 1];
            v = w0 * Kn[c * N_TOT + c00] + w1 * Kn[c * N_TOT + c01]
              + w2 * G[c * N_TOT + c10]  + w3 * G[c * N_TOT + c11];
        }
        if (n == 0) {
            bool m0 = (flag[0] == 1.0f);
            int c00 = i01[0], c01 = i01[1];
            int c10 = i01[2 * N_TOT], c11 = i01[2 * N_TOT + 1];
            float kn0 = Kn[c * N_TOT];
            float g0  = G[c * N_TOT];
            if (!(m0 && c00 == 0)) v += w0 * kn0;
            if (!(m0 && c01 == 0)) v += w1 * kn0;
            if (!(m0 && c10 == 0)) v += w2 * g0;
            if (!(m0 && c11 == 0)) v += w3 * g0;
        }
        val[e] = v;
    }
    *(float4*)&out[2 * C_DIM * N_TOT + c * N_TOT + n4] =
        make_float4(val[0], val[1], val[2], val[3]);
}

// ---------------------------------------------------------------------------
extern "C" void kernel_launch(void* const* d_in, const int* in_sizes, int n_in,
                              void* d_out, int out_size, void* d_ws, size_t ws_size,
                              hipStream_t stream) {
    const float* G    = (const float*)d_in[0];
    const float* Kn   = (const float*)d_in[1];
    const float* flag = (const float*)d_in[2];
    float* out = (float*)d_out;

    unsigned short* Phi = (unsigned short*)d_ws;                  // 8 MB each
    unsigned short* Plo = Phi + (size_t)N_TOT * C_DIM;
    unsigned short* Khi = Plo + (size_t)N_TOT * C_DIM;
    unsigned short* Klo = Khi + (size_t)N_TOT * C_DIM;
    float* dot0  = (float*)(Klo + (size_t)N_TOT * C_DIM);         // 4 MB
    float* dot1  = dot0 + (size_t)N_TOT * N_TOT;                  // 4 MB
    float* normP = dot1 + (size_t)N_TOT * N_TOT;
    float* normK = normP + N_TOT;
    float* w01   = normK + N_TOT;                                 // [2][N][2]
    int*   i01   = (int*)(w01 + 4 * N_TOT);

    // zero dot0, dot1, normP, normK in one shot (contiguous)
    const size_t zero_bytes = ((size_t)2 * N_TOT * N_TOT + 2 * N_TOT) * sizeof(float);
    hipMemsetAsync(dot0, 0, zero_bytes, stream);

    split_norms<<<dim3(64, 16, 2), 256, 0, stream>>>(G, Kn, Phi, Plo, Khi, Klo, normP, normK);
    gemm_coarse<<<dim3(16, 16, 4), 256, 0, stream>>>(Phi, Khi, dot0, dot1);
    topk_refine<<<dim3(1024, 2), 64, 0, stream>>>(dot0, dot1, Phi, Plo, Khi, Klo,
                                                  normP, normK, flag, w01, i01);
    output_kernel<<<4096, 256, 0, stream>>>(G, Kn, flag, w01, i01, out);
}

// Round 5
// 188.021 us; speedup vs baseline: 1.0575x; 1.0575x over previous
//
#include <hip/hip_runtime.h>
#include <hip/hip_bf16.h>
#include <math.h>

#define N_TOT 1024
#define C_DIM 4096
#define T_MARGIN 3e-4f   // coarse fp16 cosine err sigma ~5e-6; 3e-4 = ~56 sigma

typedef __attribute__((ext_vector_type(8))) _Float16 half8;
typedef __attribute__((ext_vector_type(8))) unsigned short ushort8;
typedef __attribute__((ext_vector_type(4))) float floatx4;

__device__ inline unsigned short f2h(float v) {
    _Float16 h = (_Float16)v;
    return __builtin_bit_cast(unsigned short, h);
}
__device__ inline float h2f(unsigned short u) {
    return (float)__builtin_bit_cast(_Float16, u);
}

// ---------------------------------------------------------------------------
// split+transpose+norms: X (C,N) fp32 -> Xhi[n][c], Xlo[n][c] fp16, and
// normX[n] += sum_c x^2 (atomic, pre-zeroed). grid (64, 16, 2).
__global__ __launch_bounds__(256) void split_norms(const float* __restrict__ G,
                                                   const float* __restrict__ Kn,
                                                   unsigned short* __restrict__ Phi,
                                                   unsigned short* __restrict__ Plo,
                                                   unsigned short* __restrict__ Khi,
                                                   unsigned short* __restrict__ Klo,
                                                   float* __restrict__ normP,
                                                   float* __restrict__ normK) {
    const int z = blockIdx.z;
    const float* X = z ? Kn : G;
    unsigned short* Xhi = z ? Khi : Phi;
    unsigned short* Xlo = z ? Klo : Plo;
    float* normX = z ? normK : normP;

    __shared__ float tile[64 * 65];
    __shared__ float np[256];
    const int t  = threadIdx.x;
    const int c0 = blockIdx.x * 64;
    const int n0 = blockIdx.y * 64;

    float s2 = 0.0f;
    #pragma unroll
    for (int s = 0; s < 16; s++) {
        int c_loc = s * 4 + (t >> 6);
        int n_loc = t & 63;
        float v = X[(c0 + c_loc) * N_TOT + n0 + n_loc];
        tile[c_loc * 65 + n_loc] = v;
        s2 = fmaf(v, v, s2);
    }
    np[t] = s2;
    __syncthreads();

    if (t < 64) {
        float tot = np[t] + np[t + 64] + np[t + 128] + np[t + 192];
        atomicAdd(&normX[n0 + t], tot);
    }

    #pragma unroll
    for (int s = 0; s < 4; s++) {
        int n_loc = s * 16 + (t >> 4);
        int c4    = (t & 15) * 4;
        unsigned short h[4], l[4];
        #pragma unroll
        for (int e = 0; e < 4; e++) {
            float v = tile[(c4 + e) * 65 + n_loc];
            h[e] = f2h(v);
            l[e] = f2h(v - h2f(h[e]));
        }
        size_t base = (size_t)(n0 + n_loc) * C_DIM + c0 + c4;
        *(ushort4*)&Xhi[base] = make_ushort4(h[0], h[1], h[2], h[3]);
        *(ushort4*)&Xlo[base] = make_ushort4(l[0], l[1], l[2], l[3]);
    }
}

// ---------------------------------------------------------------------------
// coarse hi-only fp16 MFMA GEMM against concatenated B' = [K ; P] (2048 rows,
// contiguous planes). dotAll[i][j'] = P_i . B'_j'. 128x128 tile, BK=64,
// 256 threads (4 waves, each 64x64 of the tile), K-split 4 -> grid (8,16,4)
// = 512 blocks (2/CU). atomicAdd into zeroed dotAll.
__global__ __launch_bounds__(256, 2) void gemm_coarse(const unsigned short* __restrict__ Phi,
                                                      const unsigned short* __restrict__ Bcat,
                                                      float* __restrict__ dotAll) {
    __shared__ unsigned short sA[128 * 64];   // 16 KB
    __shared__ unsigned short sB[128 * 64];   // 16 KB

    const int t    = threadIdx.x;
    const int wave = t >> 6, lane = t & 63;
    const int wm   = wave >> 1, wn = wave & 1;
    const int quad = lane >> 4, lrow = lane & 15;
    const int ib = blockIdx.x * 128, jb = blockIdx.y * 128;
    const int k_beg = blockIdx.z * 1024;

    const int srow = t >> 3;            // 0..31
    const int g    = (t & 7) ^ (srow & 7);

    const unsigned short* gA = Phi  + (size_t)(ib + srow) * C_DIM + g * 8;
    const unsigned short* gB = Bcat + (size_t)(jb + srow) * C_DIM + g * 8;
    const size_t rstep = (size_t)32 * C_DIM;

    floatx4 acc[4][4] = {};

    for (int k0 = k_beg; k0 < k_beg + 1024; k0 += 64) {
        #pragma unroll
        for (int q = 0; q < 4; q++) {
            int lds_off = q * 4096 + t * 16;   // bytes
            __builtin_amdgcn_global_load_lds(
                (const __attribute__((address_space(1))) void*)(gA + q * rstep + k0),
                (__attribute__((address_space(3))) void*)((char*)sA + lds_off), 16, 0, 0);
            __builtin_amdgcn_global_load_lds(
                (const __attribute__((address_space(1))) void*)(gB + q * rstep + k0),
                (__attribute__((address_space(3))) void*)((char*)sB + lds_off), 16, 0, 0);
        }
        __syncthreads();

        #pragma unroll
        for (int kk = 0; kk < 2; kk++) {
            const int gk = kk * 4 + quad;
            half8 a[4], b[4];
            #pragma unroll
            for (int ti = 0; ti < 4; ti++) {
                int m = wm * 64 + ti * 16 + lrow;
                a[ti] = *(const half8*)&sA[m * 64 + ((gk ^ (m & 7)) << 3)];
            }
            #pragma unroll
            for (int tj = 0; tj < 4; tj++) {
                int n = wn * 64 + tj * 16 + lrow;
                b[tj] = *(const half8*)&sB[n * 64 + ((gk ^ (n & 7)) << 3)];
            }
            #pragma unroll
            for (int ti = 0; ti < 4; ti++)
                #pragma unroll
                for (int tj = 0; tj < 4; tj++)
                    acc[ti][tj] = __builtin_amdgcn_mfma_f32_16x16x32_f16(a[ti], b[tj], acc[ti][tj], 0, 0, 0);
        }
        __syncthreads();
    }

    // C/D layout: n-index = lane&15, m-index = quad*4+reg
    #pragma unroll
    for (int tj = 0; tj < 4; tj++) {
        int j = jb + wn * 64 + tj * 16 + lrow;
        #pragma unroll
        for (int ti = 0; ti < 4; ti++) {
            #pragma unroll
            for (int reg = 0; reg < 4; reg++) {
                int i = ib + wm * 64 + ti * 16 + quad * 4 + reg;
                atomicAdd(&dotAll[(size_t)i * 2048 + j], acc[ti][tj][reg]);
            }
        }
    }
}

// ---------------------------------------------------------------------------
// coarse top-8 per (row, z) with margin test; refine in fp32 (hi+lo) only if
// the top-2 identity/order is ambiguous. grid (1024, 2), block 256.
__global__ __launch_bounds__(256) void topk_refine(const float* __restrict__ dotAll,
                                                   const unsigned short* __restrict__ Phi,
                                                   const unsigned short* __restrict__ Plo,
                                                   const unsigned short* __restrict__ Khi,
                                                   const unsigned short* __restrict__ Klo,
                                                   const float* __restrict__ normP,
                                                   const float* __restrict__ normK,
                                                   const float* __restrict__ flag,
                                                   float* __restrict__ w01,   // [2][N][2]
                                                   int* __restrict__ i01) {   // [2][N][2]
    __shared__ float sAf[C_DIM];     // 16 KB, refine A row
    __shared__ float s_bv[4];
    __shared__ int   s_bj[4];
    __shared__ float s_rcv[8];

    const int row = blockIdx.x;
    const int z   = blockIdx.y;
    const int t   = threadIdx.x;
    const int wave = t >> 6, lane = t & 63;
    const float* D  = dotAll + (size_t)row * 2048 + z * 1024;
    const float* nB = z ? normP : normK;
    const float target = z ? 1.0f : 0.0f;
    const float nr = normP[row];

    // coarse normalized cosines for this thread's 4 columns
    float4 dv = *(const float4*)(D + 4 * t);
    float4 fv = *(const float4*)(flag + 4 * t);
    float4 nv = *(const float4*)(nB + 4 * t);
    float cv[4];
    cv[0] = (fv.x == target) ? dv.x * rsqrtf(nr * nv.x) : -INFINITY;
    cv[1] = (fv.y == target) ? dv.y * rsqrtf(nr * nv.y) : -INFINITY;
    cv[2] = (fv.z == target) ? dv.z * rsqrtf(nr * nv.z) : -INFINITY;
    cv[3] = (fv.w == target) ? dv.w * rsqrtf(nr * nv.w) : -INFINITY;

    int   cand[8];
    float cval[8];
    #pragma unroll
    for (int it = 0; it < 8; it++) {
        float bv = cv[0]; int bj = 4 * t;
        #pragma unroll
        for (int e = 1; e < 4; e++) {
            int j = 4 * t + e;
            if (cv[e] > bv || (cv[e] == bv && j < bj)) { bv = cv[e]; bj = j; }
        }
        #pragma unroll
        for (int off = 32; off > 0; off >>= 1) {
            float ov = __shfl_xor(bv, off);
            int   oj = __shfl_xor(bj, off);
            if (ov > bv || (ov == bv && oj < bj)) { bv = ov; bj = oj; }
        }
        if (lane == 0) { s_bv[wave] = bv; s_bj[wave] = bj; }
        __syncthreads();
        float wv = s_bv[0]; int wj = s_bj[0];
        #pragma unroll
        for (int w = 1; w < 4; w++) {
            if (s_bv[w] > wv || (s_bv[w] == wv && s_bj[w] < wj)) { wv = s_bv[w]; wj = s_bj[w]; }
        }
        cand[it] = wj; cval[it] = wv;
        #pragma unroll
        for (int e = 0; e < 4; e++)
            if (wj == 4 * t + e) cv[e] = -INFINITY;
        __syncthreads();
    }

    const bool trust = (cval[0] - cval[1] > T_MARGIN) && (cval[1] - cval[2] > T_MARGIN);
    if (trust) {
        if (t == 0) {
            int base = (z * N_TOT + row) * 2;
            w01[base]     = cval[0];
            w01[base + 1] = cval[1];
            i01[base]     = cand[0];
            i01[base + 1] = cand[1];
        }
        return;
    }

    // ---- refine: exact fp32 dots for the 8 candidates ----
    const unsigned short* Ah = Phi + (size_t)row * C_DIM;
    const unsigned short* Al = Plo + (size_t)row * C_DIM;
    const unsigned short* Bh = z ? Phi : Khi;
    const unsigned short* Bl = z ? Plo : Klo;

    #pragma unroll
    for (int s = 0; s < 2; s++) {
        int c = t * 16 + s * 8;
        ushort8 hb = *(const ushort8*)&Ah[c];
        ushort8 lb = *(const ushort8*)&Al[c];
        #pragma unroll
        for (int e = 0; e < 8; e++) sAf[c + e] = h2f(hb[e]) + h2f(lb[e]);
    }
    __syncthreads();

    const int grp = t >> 5, l32 = t & 31;
    const unsigned short* bh_row = Bh + (size_t)cand[grp] * C_DIM;
    const unsigned short* bl_row = Bl + (size_t)cand[grp] * C_DIM;
    float acc = 0.0f;
    for (int it = 0; it < 16; it++) {
        int c = it * 256 + l32 * 8;
        ushort8 hb = *(const ushort8*)&bh_row[c];
        ushort8 lb = *(const ushort8*)&bl_row[c];
        #pragma unroll
        for (int e = 0; e < 8; e++)
            acc = fmaf(sAf[c + e], h2f(hb[e]) + h2f(lb[e]), acc);
    }
    #pragma unroll
    for (int off = 16; off > 0; off >>= 1) acc += __shfl_xor(acc, off);
    if (l32 == 0) s_rcv[grp] = acc;
    __syncthreads();

    if (t == 0) {
        float v1 = -INFINITY, v2 = -INFINITY;
        int   j1 = 0x7FFFFFFF, j2 = 0x7FFFFFFF;
        #pragma unroll
        for (int q = 0; q < 8; q++) {
            int j = cand[q];
            float cvx = s_rcv[q] * rsqrtf(nr * nB[j]);
            if (cvx > v1 || (cvx == v1 && j < j1)) {
                v2 = v1; j2 = j1; v1 = cvx; j1 = j;
            } else if (cvx > v2 || (cvx == v2 && j < j2)) {
                v2 = cvx; j2 = j;
            }
        }
        int base = (z * N_TOT + row) * 2;
        w01[base]     = v1;
        w01[base + 1] = v2;
        i01[base]     = j1;
        i01[base + 1] = j2;
    }
}

// ---------------------------------------------------------------------------
// output: inline means->softmax->weights, copy generated & known (float4),
// rtn = weighted gather. grid (4096), block 256.
__global__ __launch_bounds__(256) void output_kernel(const float* __restrict__ G,
                                                     const float* __restrict__ Kn,
                                                     const float* __restrict__ flag,
                                                     const float* __restrict__ w01,
                                                     const int* __restrict__ i01,
                                                     float* __restrict__ out) {
    __shared__ float red[5][4];
    __shared__ float wts[4];
    const int c  = blockIdx.x;
    const int t  = threadIdx.x;
    const int n4 = t * 4;

    float4 fv = *(const float4*)&flag[n4];
    const float fa[4] = {fv.x, fv.y, fv.z, fv.w};

    float pm[5] = {};
    #pragma unroll
    for (int e = 0; e < 4; e++) {
        int n = n4 + e;
        float m = fa[e];
        pm[0] += m;
        pm[1] += m * w01[n * 2 + 0];
        pm[2] += m * w01[n * 2 + 1];
        pm[3] += m * w01[2 * N_TOT + n * 2 + 0];
        pm[4] += m * w01[2 * N_TOT + n * 2 + 1];
    }
    #pragma unroll
    for (int i = 0; i < 5; i++)
        #pragma unroll
        for (int off = 32; off > 0; off >>= 1)
            pm[i] += __shfl_xor(pm[i], off);
    const int wave = t >> 6, lane = t & 63;
    if (lane == 0) {
        #pragma unroll
        for (int i = 0; i < 5; i++) red[i][wave] = pm[i];
    }
    __syncthreads();
    if (t == 0) {
        float tot[5];
        #pragma unroll
        for (int i = 0; i < 5; i++)
            tot[i] = red[i][0] + red[i][1] + red[i][2] + red[i][3];
        float inv = 1.0f / tot[0];
        float mv[4] = {tot[1] * inv, tot[2] * inv, tot[3] * inv, tot[4] * inv};
        float mx = fmaxf(fmaxf(mv[0], mv[1]), fmaxf(mv[2], mv[3]));
        float e[4], s = 0.0f;
        #pragma unroll
        for (int q = 0; q < 4; q++) { e[q] = expf(mv[q] - mx); s += e[q]; }
        #pragma unroll
        for (int q = 0; q < 4; q++) wts[q] = e[q] / s;
    }
    __syncthreads();
    const float w0 = wts[0], w1 = wts[1], w2 = wts[2], w3 = wts[3];

    float4 gv = *(const float4*)&G[c * N_TOT + n4];
    float4 kv = *(const float4*)&Kn[c * N_TOT + n4];
    *(float4*)&out[c * N_TOT + n4] = gv;
    *(float4*)&out[C_DIM * N_TOT + c * N_TOT + n4] = kv;

    float val[4];
    #pragma unroll
    for (int e = 0; e < 4; e++) {
        int n = n4 + e;
        float v = 0.0f;
        if (fa[e] == 1.0f) {
            int c00 = i01[n * 2 + 0];
            int c01 = i01[n * 2 + 1];
            int c10 = i01[2 * N_TOT + n * 2 + 0];
            int c11 = i01[2 * N_TOT + n * 2 + 1];
            v = w0 * Kn[c * N_TOT + c00] + w1 * Kn[c * N_TOT + c01]
              + w2 * G[c * N_TOT + c10]  + w3 * G[c * N_TOT + c11];
        }
        if (n == 0) {
            bool m0 = (flag[0] == 1.0f);
            int c00 = i01[0], c01 = i01[1];
            int c10 = i01[2 * N_TOT], c11 = i01[2 * N_TOT + 1];
            float kn0 = Kn[c * N_TOT];
            float g0  = G[c * N_TOT];
            if (!(m0 && c00 == 0)) v += w0 * kn0;
            if (!(m0 && c01 == 0)) v += w1 * kn0;
            if (!(m0 && c10 == 0)) v += w2 * g0;
            if (!(m0 && c11 == 0)) v += w3 * g0;
        }
        val[e] = v;
    }
    *(float4*)&out[2 * C_DIM * N_TOT + c * N_TOT + n4] =
        make_float4(val[0], val[1], val[2], val[3]);
}

// ---------------------------------------------------------------------------
extern "C" void kernel_launch(void* const* d_in, const int* in_sizes, int n_in,
                              void* d_out, int out_size, void* d_ws, size_t ws_size,
                              hipStream_t stream) {
    const float* G    = (const float*)d_in[0];
    const float* Kn   = (const float*)d_in[1];
    const float* flag = (const float*)d_in[2];
    float* out = (float*)d_out;

    // ws: Khi | Phi contiguous (B' concat), then lo planes, dotAll, smalls.
    unsigned short* Khi = (unsigned short*)d_ws;                  // 8 MB each
    unsigned short* Phi = Khi + (size_t)N_TOT * C_DIM;
    unsigned short* Klo = Phi + (size_t)N_TOT * C_DIM;
    unsigned short* Plo = Klo + (size_t)N_TOT * C_DIM;
    float* dotAll = (float*)(Plo + (size_t)N_TOT * C_DIM);        // 8 MB
    float* normP  = dotAll + (size_t)N_TOT * 2048;
    float* normK  = normP + N_TOT;
    float* w01    = normK + N_TOT;                                // [2][N][2]
    int*   i01    = (int*)(w01 + 4 * N_TOT);

    // zero dotAll + normP + normK (contiguous)
    const size_t zero_bytes = ((size_t)N_TOT * 2048 + 2 * N_TOT) * sizeof(float);
    hipMemsetAsync(dotAll, 0, zero_bytes, stream);

    split_norms<<<dim3(64, 16, 2), 256, 0, stream>>>(G, Kn, Phi, Plo, Khi, Klo, normP, normK);
    gemm_coarse<<<dim3(8, 16, 4), 256, 0, stream>>>(Phi, Khi /* B' = [K;P] */, dotAll);
    topk_refine<<<dim3(1024, 2), 256, 0, stream>>>(dotAll, Phi, Plo, Khi, Klo,
                                                   normP, normK, flag, w01, i01);
    output_kernel<<<4096, 256, 0, stream>>>(G, Kn, flag, w01, i01, out);
}

// Round 6
// 185.997 us; speedup vs baseline: 1.0690x; 1.0109x over previous
//
#include <hip/hip_runtime.h>
#include <hip/hip_bf16.h>
#include <math.h>

#define N_TOT 1024
#define C_DIM 4096
#define T_MARGIN 3e-4f   // coarse fp16 cosine err sigma ~6e-6; 3e-4 = ~50 sigma

typedef __attribute__((ext_vector_type(8))) _Float16 half8;
typedef __attribute__((ext_vector_type(8))) unsigned short ushort8;
typedef __attribute__((ext_vector_type(8))) char schar8;
typedef __attribute__((ext_vector_type(4))) float floatx4;

__device__ inline unsigned short f2h(float v) {
    _Float16 h = (_Float16)v;
    return __builtin_bit_cast(unsigned short, h);
}
__device__ inline float h2f(unsigned short u) {
    return (float)__builtin_bit_cast(_Float16, u);
}
// int8 residual with exponent borrowed from the fp16 hi part:
//   lo = v - h2f(hi), |lo| <= ulp(hi)/2 = 2^(e-26)  (e = fp16 exponent field)
//   q  = rint(lo * 240 * 2^(25-e))  in [-120, 120]
// decode: lo ~= q * 2^(e-25) / 240   -> residual error ~ ulp/480: cos err ~1e-9
__device__ inline char lo_enc(float v, unsigned short h) {
    int e = (h >> 10) & 31;
    float lo = v - h2f(h);
    float q = rintf(lo * 240.0f * __uint_as_float((unsigned)(152 - e) << 23));
    q = fmaxf(-127.0f, fminf(127.0f, q));
    return (char)(int)q;
}
__device__ inline float lo_dec(char q, unsigned short h) {
    int e = (h >> 10) & 31;
    return (float)q * __uint_as_float((unsigned)(e + 102) << 23) * (1.0f / 240.0f);
}

// ---------------------------------------------------------------------------
// flag scan: colidx[0..n0) = cols with flag==0 (ascending), colidx[n0..1024) =
// cols with flag==1 (ascending); *n0p = #zeros. one block, 256 threads.
__global__ __launch_bounds__(256) void flagscan(const float* __restrict__ flag,
                                                int* __restrict__ colidx,
                                                int* __restrict__ n0p) {
    __shared__ int cz[256];
    __shared__ int co[256];
    const int t = threadIdx.x;
    float4 fv = *(const float4*)&flag[4 * t];
    int f[4] = {fv.x == 0.0f, fv.y == 0.0f, fv.z == 0.0f, fv.w == 0.0f};
    int nz = f[0] + f[1] + f[2] + f[3];
    cz[t] = nz; co[t] = 4 - nz;
    __syncthreads();
    for (int off = 1; off < 256; off <<= 1) {
        int vz = (t >= off) ? cz[t - off] : 0;
        int vo = (t >= off) ? co[t - off] : 0;
        __syncthreads();
        cz[t] += vz; co[t] += vo;
        __syncthreads();
    }
    const int n0 = cz[255];
    int zs = cz[t] - nz;              // zeros before my chunk
    int os = n0 + co[t] - (4 - nz);   // ones slot base
    #pragma unroll
    for (int e = 0; e < 4; e++) {
        int j = 4 * t + e;
        if (f[e]) colidx[zs++] = j;
        else      colidx[os++] = j;
    }
    if (t == 0) *n0p = n0;
}

// ---------------------------------------------------------------------------
// split+transpose+norms: X (C,N) fp32 -> Xhi[n][c] fp16, Xlo[n][c] int8
// residual; normX[n] += sum_c x^2 (atomic, pre-zeroed). grid (64, 16, 2).
__global__ __launch_bounds__(256) void split_norms(const float* __restrict__ G,
                                                   const float* __restrict__ Kn,
                                                   unsigned short* __restrict__ Phi,
                                                   char* __restrict__ Plo,
                                                   unsigned short* __restrict__ Khi,
                                                   char* __restrict__ Klo,
                                                   float* __restrict__ normP,
                                                   float* __restrict__ normK) {
    const int z = blockIdx.z;
    const float* X = z ? Kn : G;
    unsigned short* Xhi = z ? Khi : Phi;
    char* Xlo = z ? Klo : Plo;
    float* normX = z ? normK : normP;

    __shared__ float tile[64 * 65];
    __shared__ float np[256];
    const int t  = threadIdx.x;
    const int c0 = blockIdx.x * 64;
    const int n0 = blockIdx.y * 64;

    float s2 = 0.0f;
    #pragma unroll
    for (int s = 0; s < 16; s++) {
        int c_loc = s * 4 + (t >> 6);
        int n_loc = t & 63;
        float v = X[(c0 + c_loc) * N_TOT + n0 + n_loc];
        tile[c_loc * 65 + n_loc] = v;
        s2 = fmaf(v, v, s2);
    }
    np[t] = s2;
    __syncthreads();

    if (t < 64) {
        float tot = np[t] + np[t + 64] + np[t + 128] + np[t + 192];
        atomicAdd(&normX[n0 + t], tot);
    }

    #pragma unroll
    for (int s = 0; s < 4; s++) {
        int n_loc = s * 16 + (t >> 4);
        int c4    = (t & 15) * 4;
        unsigned short h[4]; char l[4];
        #pragma unroll
        for (int e = 0; e < 4; e++) {
            float v = tile[(c4 + e) * 65 + n_loc];
            h[e] = f2h(v);
            l[e] = lo_enc(v, h[e]);
        }
        size_t base = (size_t)(n0 + n_loc) * C_DIM + c0 + c4;
        *(ushort4*)&Xhi[base] = make_ushort4(h[0], h[1], h[2], h[3]);
        *(char4*)&Xlo[base]   = make_char4(l[0], l[1], l[2], l[3]);
    }
}

// ---------------------------------------------------------------------------
// coarse fp16 MFMA GEMM vs VIRTUALLY-COMPACTED B: column slot s of dotSel is
// row colidx[s] of (s<n0 ? K : P). Compaction costs nothing: global_load_lds
// takes per-lane global addresses. 64x128 tile, BK=64, K-split 8 ->
// grid (16,8,8) = 1024 blocks, 24 KB LDS, 4 blocks/CU. atomicAdd epilogue.
__global__ __launch_bounds__(256, 4) void gemm_coarse(const unsigned short* __restrict__ Phi,
                                                      const unsigned short* __restrict__ Khi,
                                                      const int* __restrict__ colidx,
                                                      const int* __restrict__ n0p,
                                                      float* __restrict__ dotSel) {
    __shared__ unsigned short sA[64 * 64];    // 8 KB
    __shared__ unsigned short sB[128 * 64];   // 16 KB

    const int t    = threadIdx.x;
    const int wave = t >> 6, lane = t & 63;
    const int wm   = wave >> 1, wn = wave & 1;
    const int quad = lane >> 4, lrow = lane & 15;
    const int ib = blockIdx.x * 64, jb = blockIdx.y * 128;
    const int k_beg = blockIdx.z * 512;
    const int n0 = *n0p;

    const int srow = t >> 3;            // 0..31
    const int g    = (t & 7) ^ (srow & 7);

    const unsigned short* gA[2];
    gA[0] = Phi + (size_t)(ib + srow) * C_DIM + g * 8;
    gA[1] = gA[0] + (size_t)32 * C_DIM;
    const unsigned short* gB[4];
    #pragma unroll
    for (int q = 0; q < 4; q++) {
        int s = jb + q * 32 + srow;
        int row = colidx[s];
        const unsigned short* src = (s < n0) ? Khi : Phi;
        gB[q] = src + (size_t)row * C_DIM + g * 8;
    }

    floatx4 acc[2][4] = {};

    for (int k0 = k_beg; k0 < k_beg + 512; k0 += 64) {
        #pragma unroll
        for (int q = 0; q < 2; q++)
            __builtin_amdgcn_global_load_lds(
                (const __attribute__((address_space(1))) void*)(gA[q] + k0),
                (__attribute__((address_space(3))) void*)((char*)sA + q * 4096 + t * 16), 16, 0, 0);
        #pragma unroll
        for (int q = 0; q < 4; q++)
            __builtin_amdgcn_global_load_lds(
                (const __attribute__((address_space(1))) void*)(gB[q] + k0),
                (__attribute__((address_space(3))) void*)((char*)sB + q * 4096 + t * 16), 16, 0, 0);
        __syncthreads();

        #pragma unroll
        for (int kk = 0; kk < 2; kk++) {
            const int gk = kk * 4 + quad;
            half8 a[2], b[4];
            #pragma unroll
            for (int ti = 0; ti < 2; ti++) {
                int m = wm * 32 + ti * 16 + lrow;
                a[ti] = *(const half8*)&sA[m * 64 + ((gk ^ (m & 7)) << 3)];
            }
            #pragma unroll
            for (int tj = 0; tj < 4; tj++) {
                int n = wn * 64 + tj * 16 + lrow;
                b[tj] = *(const half8*)&sB[n * 64 + ((gk ^ (n & 7)) << 3)];
            }
            #pragma unroll
            for (int ti = 0; ti < 2; ti++)
                #pragma unroll
                for (int tj = 0; tj < 4; tj++)
                    acc[ti][tj] = __builtin_amdgcn_mfma_f32_16x16x32_f16(a[ti], b[tj], acc[ti][tj], 0, 0, 0);
        }
        __syncthreads();
    }

    // C/D layout: col = lane&15, row = quad*4+reg
    #pragma unroll
    for (int tj = 0; tj < 4; tj++) {
        int j = jb + wn * 64 + tj * 16 + lrow;
        #pragma unroll
        for (int ti = 0; ti < 2; ti++) {
            #pragma unroll
            for (int reg = 0; reg < 4; reg++) {
                int i = ib + wm * 32 + ti * 16 + quad * 4 + reg;
                atomicAdd(&dotSel[(size_t)i * N_TOT + j], acc[ti][tj][reg]);
            }
        }
    }
}

// ---------------------------------------------------------------------------
// coarse top-8 over the z-part of the compacted columns; margin-gated exact
// refine (fp16 hi + exp-coded int8 lo -> ~1e-9 cosine). grid (1024, 2).
__global__ __launch_bounds__(256) void topk_refine(const float* __restrict__ dotSel,
                                                   const unsigned short* __restrict__ Phi,
                                                   const char* __restrict__ Plo,
                                                   const unsigned short* __restrict__ Khi,
                                                   const char* __restrict__ Klo,
                                                   const float* __restrict__ normP,
                                                   const float* __restrict__ normK,
                                                   const int* __restrict__ colidx,
                                                   const int* __restrict__ n0p,
                                                   float* __restrict__ w01,   // [2][N][2]
                                                   int* __restrict__ i01) {   // [2][N][2]
    __shared__ float sAf[C_DIM];     // 16 KB refine A row
    __shared__ float s_bv[4];
    __shared__ int   s_bj[4];
    __shared__ float s_rcv[8];

    const int row = blockIdx.x;
    const int z   = blockIdx.y;
    const int t   = threadIdx.x;
    const int wave = t >> 6, lane = t & 63;
    const int n0 = *n0p;
    const float nr = normP[row];

    // coarse cosines for my 4 compacted slots (masked to my z-part)
    float4 dv = *(const float4*)&dotSel[(size_t)row * N_TOT + 4 * t];
    float cv[4];
    #pragma unroll
    for (int e = 0; e < 4; e++) {
        int s = 4 * t + e;
        bool inz = z ? (s >= n0) : (s < n0);
        if (inz) {
            int gj = colidx[s];
            float nb = (s < n0) ? normK[gj] : normP[gj];
            cv[e] = dv[e] * rsqrtf(nr * nb);
        } else cv[e] = -INFINITY;
    }

    int   cand[8];
    float cval[8];
    #pragma unroll
    for (int it = 0; it < 8; it++) {
        float bv = cv[0]; int bj = 4 * t;
        #pragma unroll
        for (int e = 1; e < 4; e++) {
            int j = 4 * t + e;
            if (cv[e] > bv || (cv[e] == bv && j < bj)) { bv = cv[e]; bj = j; }
        }
        #pragma unroll
        for (int off = 32; off > 0; off >>= 1) {
            float ov = __shfl_xor(bv, off);
            int   oj = __shfl_xor(bj, off);
            if (ov > bv || (ov == bv && oj < bj)) { bv = ov; bj = oj; }
        }
        if (lane == 0) { s_bv[wave] = bv; s_bj[wave] = bj; }
        __syncthreads();
        float wv = s_bv[0]; int wj = s_bj[0];
        #pragma unroll
        for (int w = 1; w < 4; w++)
            if (s_bv[w] > wv || (s_bv[w] == wv && s_bj[w] < wj)) { wv = s_bv[w]; wj = s_bj[w]; }
        cand[it] = wj; cval[it] = wv;
        #pragma unroll
        for (int e = 0; e < 4; e++)
            if (wj == 4 * t + e) cv[e] = -INFINITY;
        __syncthreads();
    }

    // margin test (coarse err ~6e-6 << T_MARGIN). -inf at cval[2] => +inf gap.
    const bool trust = (cval[0] - cval[1] > T_MARGIN) && (cval[1] - cval[2] > T_MARGIN);
    if (trust) {
        if (t == 0) {
            int base = (z * N_TOT + row) * 2;
            w01[base]     = cval[0];
            w01[base + 1] = cval[1];
            i01[base]     = colidx[cand[0]];
            i01[base + 1] = colidx[cand[1]];
        }
        return;
    }

    // ---- refine: near-exact dots for the 8 candidates ----
    {
        const unsigned short* Ah = Phi + (size_t)row * C_DIM;
        const char*           Al = Plo + (size_t)row * C_DIM;
        #pragma unroll
        for (int s = 0; s < 2; s++) {
            int c = t * 16 + s * 8;
            ushort8 hb = *(const ushort8*)&Ah[c];
            schar8  lb = *(const schar8*)&Al[c];
            #pragma unroll
            for (int e = 0; e < 8; e++) sAf[c + e] = h2f(hb[e]) + lo_dec(lb[e], hb[e]);
        }
    }
    __syncthreads();

    const int grp = t >> 5, l32 = t & 31;
    const int cs  = cand[grp];
    const int gj  = colidx[cs];
    const unsigned short* bh_row = ((cs < n0) ? Khi : Phi) + (size_t)gj * C_DIM;
    const char*           bl_row = ((cs < n0) ? Klo : Plo) + (size_t)gj * C_DIM;
    float acc = 0.0f;
    for (int it = 0; it < 16; it++) {
        int c = it * 256 + l32 * 8;
        ushort8 hb = *(const ushort8*)&bh_row[c];
        schar8  lb = *(const schar8*)&bl_row[c];
        #pragma unroll
        for (int e = 0; e < 8; e++)
            acc = fmaf(sAf[c + e], h2f(hb[e]) + lo_dec(lb[e], hb[e]), acc);
    }
    #pragma unroll
    for (int off = 16; off > 0; off >>= 1) acc += __shfl_xor(acc, off);
    if (l32 == 0) s_rcv[grp] = acc;
    __syncthreads();

    if (t == 0) {
        float v1 = -INFINITY, v2 = -INFINITY;
        int   j1 = 0x7FFFFFFF, j2 = 0x7FFFFFFF;
        #pragma unroll
        for (int q = 0; q < 8; q++) {
            if (!(cval[q] > -1e29f)) continue;   // slot not in this z-part
            int s = cand[q];
            int gjx = colidx[s];
            float nb = (s < n0) ? normK[gjx] : normP[gjx];
            float cvx = s_rcv[q] * rsqrtf(nr * nb);
            int j = gjx;
            if (cvx > v1 || (cvx == v1 && j < j1)) {
                v2 = v1; j2 = j1; v1 = cvx; j1 = j;
            } else if (cvx > v2 || (cvx == v2 && j < j2)) {
                v2 = cvx; j2 = j;
            }
        }
        int base = (z * N_TOT + row) * 2;
        w01[base]     = v1;
        w01[base + 1] = v2;
        i01[base]     = j1;
        i01[base + 1] = j2;
    }
}

// ---------------------------------------------------------------------------
// output: inline means->softmax->weights, copy generated & known (float4),
// rtn = weighted gather. grid (4096), block 256.
__global__ __launch_bounds__(256) void output_kernel(const float* __restrict__ G,
                                                     const float* __restrict__ Kn,
                                                     const float* __restrict__ flag,
                                                     const float* __restrict__ w01,
                                                     const int* __restrict__ i01,
                                                     float* __restrict__ out) {
    __shared__ float red[5][4];
    __shared__ float wts[4];
    const int c  = blockIdx.x;
    const int t  = threadIdx.x;
    const int n4 = t * 4;

    float4 fv = *(const float4*)&flag[n4];
    const float fa[4] = {fv.x, fv.y, fv.z, fv.w};

    float pm[5] = {};
    #pragma unroll
    for (int e = 0; e < 4; e++) {
        int n = n4 + e;
        float m = fa[e];
        pm[0] += m;
        pm[1] += m * w01[n * 2 + 0];
        pm[2] += m * w01[n * 2 + 1];
        pm[3] += m * w01[2 * N_TOT + n * 2 + 0];
        pm[4] += m * w01[2 * N_TOT + n * 2 + 1];
    }
    #pragma unroll
    for (int i = 0; i < 5; i++)
        #pragma unroll
        for (int off = 32; off > 0; off >>= 1)
            pm[i] += __shfl_xor(pm[i], off);
    const int wave = t >> 6, lane = t & 63;
    if (lane == 0) {
        #pragma unroll
        for (int i = 0; i < 5; i++) red[i][wave] = pm[i];
    }
    __syncthreads();
    if (t == 0) {
        float tot[5];
        #pragma unroll
        for (int i = 0; i < 5; i++)
            tot[i] = red[i][0] + red[i][1] + red[i][2] + red[i][3];
        float inv = 1.0f / tot[0];
        float mv[4] = {tot[1] * inv, tot[2] * inv, tot[3] * inv, tot[4] * inv};
        float mx = fmaxf(fmaxf(mv[0], mv[1]), fmaxf(mv[2], mv[3]));
        float e[4], s = 0.0f;
        #pragma unroll
        for (int q = 0; q < 4; q++) { e[q] = expf(mv[q] - mx); s += e[q]; }
        #pragma unroll
        for (int q = 0; q < 4; q++) wts[q] = e[q] / s;
    }
    __syncthreads();
    const float w0 = wts[0], w1 = wts[1], w2 = wts[2], w3 = wts[3];

    float4 gv = *(const float4*)&G[c * N_TOT + n4];
    float4 kv = *(const float4*)&Kn[c * N_TOT + n4];
    *(float4*)&out[c * N_TOT + n4] = gv;
    *(float4*)&out[C_DIM * N_TOT + c * N_TOT + n4] = kv;

    float val[4];
    #pragma unroll
    for (int e = 0; e < 4; e++) {
        int n = n4 + e;
        float v = 0.0f;
        if (fa[e] == 1.0f) {
            int c00 = i01[n * 2 + 0];
            int c01 = i01[n * 2 + 1];
            int c10 = i01[2 * N_TOT + n * 2 + 0];
            int c11 = i01[2 * N_TOT + n * 2 + 1];
            v = w0 * Kn[c * N_TOT + c00] + w1 * Kn[c * N_TOT + c01]
              + w2 * G[c * N_TOT + c10]  + w3 * G[c * N_TOT + c11];
        }
        if (n == 0) {
            bool m0 = (flag[0] == 1.0f);
            int c00 = i01[0], c01 = i01[1];
            int c10 = i01[2 * N_TOT], c11 = i01[2 * N_TOT + 1];
            float kn0 = Kn[c * N_TOT];
            float g0  = G[c * N_TOT];
            if (!(m0 && c00 == 0)) v += w0 * kn0;
            if (!(m0 && c01 == 0)) v += w1 * kn0;
            if (!(m0 && c10 == 0)) v += w2 * g0;
            if (!(m0 && c11 == 0)) v += w3 * g0;
        }
        val[e] = v;
    }
    *(float4*)&out[2 * C_DIM * N_TOT + c * N_TOT + n4] =
        make_float4(val[0], val[1], val[2], val[3]);
}

// ---------------------------------------------------------------------------
extern "C" void kernel_launch(void* const* d_in, const int* in_sizes, int n_in,
                              void* d_out, int out_size, void* d_ws, size_t ws_size,
                              hipStream_t stream) {
    const float* G    = (const float*)d_in[0];
    const float* Kn   = (const float*)d_in[1];
    const float* flag = (const float*)d_in[2];
    float* out = (float*)d_out;

    // ws layout (28.05 MB total; smaller ws => cheaper per-iter re-poison)
    char* p = (char*)d_ws;
    unsigned short* Phi = (unsigned short*)p;  p += (size_t)N_TOT * C_DIM * 2;  // 8 MB
    unsigned short* Khi = (unsigned short*)p;  p += (size_t)N_TOT * C_DIM * 2;  // 8 MB
    char* Plo = p;                             p += (size_t)N_TOT * C_DIM;      // 4 MB
    char* Klo = p;                             p += (size_t)N_TOT * C_DIM;      // 4 MB
    float* dotSel = (float*)p;                 p += (size_t)N_TOT * N_TOT * 4;  // 4 MB
    float* normP  = (float*)p;                 p += N_TOT * 4;
    float* normK  = (float*)p;                 p += N_TOT * 4;
    float* w01    = (float*)p;                 p += 4 * N_TOT * 4;
    int*   i01    = (int*)p;                   p += 4 * N_TOT * 4;
    int*   colidx = (int*)p;                   p += N_TOT * 4;
    int*   n0p    = (int*)p;

    // zero dotSel + normP + normK (contiguous)
    const size_t zero_bytes = ((size_t)N_TOT * N_TOT + 2 * N_TOT) * sizeof(float);
    hipMemsetAsync(dotSel, 0, zero_bytes, stream);

    flagscan<<<1, 256, 0, stream>>>(flag, colidx, n0p);
    split_norms<<<dim3(64, 16, 2), 256, 0, stream>>>(G, Kn, Phi, Plo, Khi, Klo, normP, normK);
    gemm_coarse<<<dim3(16, 8, 8), 256, 0, stream>>>(Phi, Khi, colidx, n0p, dotSel);
    topk_refine<<<dim3(1024, 2), 256, 0, stream>>>(dotSel, Phi, Plo, Khi, Klo,
                                                   normP, normK, colidx, n0p, w01, i01);
    output_kernel<<<4096, 256, 0, stream>>>(G, Kn, flag, w01, i01, out);
}

// Round 7
// 176.023 us; speedup vs baseline: 1.1296x; 1.0567x over previous
//
#include <hip/hip_runtime.h>
#include <hip/hip_bf16.h>
#include <math.h>

#define N_TOT 1024
#define C_DIM 4096
#define T_MARGIN 3e-4f   // coarse fp16 cosine err sigma ~6e-6; 3e-4 = ~50 sigma

typedef __attribute__((ext_vector_type(8))) _Float16 half8;
typedef __attribute__((ext_vector_type(8))) unsigned short ushort8;
typedef __attribute__((ext_vector_type(8))) char schar8;
typedef __attribute__((ext_vector_type(4))) float floatx4;

__device__ inline unsigned short f2h(float v) {
    _Float16 h = (_Float16)v;
    return __builtin_bit_cast(unsigned short, h);
}
__device__ inline float h2f(unsigned short u) {
    return (float)__builtin_bit_cast(_Float16, u);
}
// int8 residual with exponent borrowed from the fp16 hi part (err ~ulp/480).
__device__ inline char lo_enc(float v, unsigned short h) {
    int e = (h >> 10) & 31;
    float lo = v - h2f(h);
    float q = rintf(lo * 240.0f * __uint_as_float((unsigned)(152 - e) << 23));
    q = fmaxf(-127.0f, fminf(127.0f, q));
    return (char)(int)q;
}
__device__ inline float lo_dec(char q, unsigned short h) {
    int e = (h >> 10) & 31;
    return (float)q * __uint_as_float((unsigned)(e + 102) << 23) * (1.0f / 240.0f);
}

// ---------------------------------------------------------------------------
// split+transpose+norms: X (C,N) fp32 -> Xhi[n][c] fp16, Xlo[n][c] int8;
// normX[n] += sum_c x^2 (atomic, pre-zeroed). Block (0,0,0) additionally
// computes the flag compaction (colidx, n0). grid (64, 16, 2).
__global__ __launch_bounds__(256) void split_norms(const float* __restrict__ G,
                                                   const float* __restrict__ Kn,
                                                   const float* __restrict__ flag,
                                                   unsigned short* __restrict__ Phi,
                                                   char* __restrict__ Plo,
                                                   unsigned short* __restrict__ Khi,
                                                   char* __restrict__ Klo,
                                                   float* __restrict__ normP,
                                                   float* __restrict__ normK,
                                                   int* __restrict__ colidx,
                                                   int* __restrict__ n0p) {
    const int z = blockIdx.z;
    const float* X = z ? Kn : G;
    unsigned short* Xhi = z ? Khi : Phi;
    char* Xlo = z ? Klo : Plo;
    float* normX = z ? normK : normP;

    __shared__ float tile[64 * 65];
    __shared__ float np[256];
    const int t  = threadIdx.x;
    const int c0 = blockIdx.x * 64;
    const int n0 = blockIdx.y * 64;

    float s2 = 0.0f;
    #pragma unroll
    for (int s = 0; s < 16; s++) {
        int c_loc = s * 4 + (t >> 6);
        int n_loc = t & 63;
        float v = X[(c0 + c_loc) * N_TOT + n0 + n_loc];
        tile[c_loc * 65 + n_loc] = v;
        s2 = fmaf(v, v, s2);
    }
    np[t] = s2;
    __syncthreads();

    if (t < 64) {
        float tot = np[t] + np[t + 64] + np[t + 128] + np[t + 192];
        atomicAdd(&normX[n0 + t], tot);
    }

    #pragma unroll
    for (int s = 0; s < 4; s++) {
        int n_loc = s * 16 + (t >> 4);
        int c4    = (t & 15) * 4;
        unsigned short h[4]; char l[4];
        #pragma unroll
        for (int e = 0; e < 4; e++) {
            float v = tile[(c4 + e) * 65 + n_loc];
            h[e] = f2h(v);
            l[e] = lo_enc(v, h[e]);
        }
        size_t base = (size_t)(n0 + n_loc) * C_DIM + c0 + c4;
        *(ushort4*)&Xhi[base] = make_ushort4(h[0], h[1], h[2], h[3]);
        *(char4*)&Xlo[base]   = make_char4(l[0], l[1], l[2], l[3]);
    }

    // ---- embedded flag scan (block (0,0,0) only; block-uniform branch) ----
    if (blockIdx.x == 0 && blockIdx.y == 0 && blockIdx.z == 0) {
        __shared__ int cz[256];
        __shared__ int co[256];
        float4 fv = *(const float4*)&flag[4 * t];
        int f[4] = {fv.x == 0.0f, fv.y == 0.0f, fv.z == 0.0f, fv.w == 0.0f};
        int nz = f[0] + f[1] + f[2] + f[3];
        cz[t] = nz; co[t] = 4 - nz;
        __syncthreads();
        for (int off = 1; off < 256; off <<= 1) {
            int vz = (t >= off) ? cz[t - off] : 0;
            int vo = (t >= off) ? co[t - off] : 0;
            __syncthreads();
            cz[t] += vz; co[t] += vo;
            __syncthreads();
        }
        const int fn0 = cz[255];
        int zs = cz[t] - nz;
        int os = fn0 + co[t] - (4 - nz);
        #pragma unroll
        for (int e = 0; e < 4; e++) {
            int j = 4 * t + e;
            if (f[e]) colidx[zs++] = j;
            else      colidx[os++] = j;
        }
        if (t == 0) *n0p = fn0;
    }
}

// ---------------------------------------------------------------------------
// coarse fp16 MFMA GEMM vs virtually-compacted B (slot s -> row colidx[s] of
// (s<n0 ? K : P)). 64x128 tile, BK=64, K-split 8 -> grid (16,8,8) = 1024
// blocks, 24 KB LDS, 4 blocks/CU. PLAIN STORES to per-z partial planes
// (each element written once -> no atomics, no zeroing).
__global__ __launch_bounds__(256, 4) void gemm_coarse(const unsigned short* __restrict__ Phi,
                                                      const unsigned short* __restrict__ Khi,
                                                      const int* __restrict__ colidx,
                                                      const int* __restrict__ n0p,
                                                      float* __restrict__ dotPart) {
    __shared__ unsigned short sA[64 * 64];    // 8 KB
    __shared__ unsigned short sB[128 * 64];   // 16 KB

    const int t    = threadIdx.x;
    const int wave = t >> 6, lane = t & 63;
    const int wm   = wave >> 1, wn = wave & 1;
    const int quad = lane >> 4, lrow = lane & 15;
    const int ib = blockIdx.x * 64, jb = blockIdx.y * 128;
    const int bz = blockIdx.z;
    const int k_beg = bz * 512;
    const int n0 = *n0p;

    const int srow = t >> 3;            // 0..31
    const int g    = (t & 7) ^ (srow & 7);

    const unsigned short* gA[2];
    gA[0] = Phi + (size_t)(ib + srow) * C_DIM + g * 8;
    gA[1] = gA[0] + (size_t)32 * C_DIM;
    const unsigned short* gB[4];
    #pragma unroll
    for (int q = 0; q < 4; q++) {
        int s = jb + q * 32 + srow;
        int row = colidx[s];
        const unsigned short* src = (s < n0) ? Khi : Phi;
        gB[q] = src + (size_t)row * C_DIM + g * 8;
    }

    floatx4 acc[2][4] = {};

    for (int k0 = k_beg; k0 < k_beg + 512; k0 += 64) {
        #pragma unroll
        for (int q = 0; q < 2; q++)
            __builtin_amdgcn_global_load_lds(
                (const __attribute__((address_space(1))) void*)(gA[q] + k0),
                (__attribute__((address_space(3))) void*)((char*)sA + q * 4096 + t * 16), 16, 0, 0);
        #pragma unroll
        for (int q = 0; q < 4; q++)
            __builtin_amdgcn_global_load_lds(
                (const __attribute__((address_space(1))) void*)(gB[q] + k0),
                (__attribute__((address_space(3))) void*)((char*)sB + q * 4096 + t * 16), 16, 0, 0);
        __syncthreads();

        #pragma unroll
        for (int kk = 0; kk < 2; kk++) {
            const int gk = kk * 4 + quad;
            half8 a[2], b[4];
            #pragma unroll
            for (int ti = 0; ti < 2; ti++) {
                int m = wm * 32 + ti * 16 + lrow;
                a[ti] = *(const half8*)&sA[m * 64 + ((gk ^ (m & 7)) << 3)];
            }
            #pragma unroll
            for (int tj = 0; tj < 4; tj++) {
                int n = wn * 64 + tj * 16 + lrow;
                b[tj] = *(const half8*)&sB[n * 64 + ((gk ^ (n & 7)) << 3)];
            }
            #pragma unroll
            for (int ti = 0; ti < 2; ti++)
                #pragma unroll
                for (int tj = 0; tj < 4; tj++)
                    acc[ti][tj] = __builtin_amdgcn_mfma_f32_16x16x32_f16(a[ti], b[tj], acc[ti][tj], 0, 0, 0);
        }
        __syncthreads();
    }

    // plain stores into this z's private plane. C/D: col=lane&15, row=quad*4+reg
    float* outp = dotPart + ((size_t)bz << 20);
    #pragma unroll
    for (int tj = 0; tj < 4; tj++) {
        int j = jb + wn * 64 + tj * 16 + lrow;
        #pragma unroll
        for (int ti = 0; ti < 2; ti++) {
            #pragma unroll
            for (int reg = 0; reg < 4; reg++) {
                int i = ib + wm * 32 + ti * 16 + quad * 4 + reg;
                outp[i * N_TOT + j] = acc[ti][tj][reg];
            }
        }
    }
}

// ---------------------------------------------------------------------------
// one block per row: sum 8 partial planes, coarse cosines, top-8 for BOTH z
// (slots partition by n0), margin-gated exact refine per z. grid (1024).
__global__ __launch_bounds__(256) void topk_refine(const float* __restrict__ dotPart,
                                                   const unsigned short* __restrict__ Phi,
                                                   const char* __restrict__ Plo,
                                                   const unsigned short* __restrict__ Khi,
                                                   const char* __restrict__ Klo,
                                                   const float* __restrict__ normP,
                                                   const float* __restrict__ normK,
                                                   const int* __restrict__ colidx,
                                                   const int* __restrict__ n0p,
                                                   float* __restrict__ w01,   // [2][N][2]
                                                   int* __restrict__ i01) {   // [2][N][2]
    __shared__ float sAf[C_DIM];     // 16 KB refine A row
    __shared__ float s_bv[4];
    __shared__ int   s_bj[4];
    __shared__ float s_rcv[8];

    const int row = blockIdx.x;
    const int t   = threadIdx.x;
    const int wave = t >> 6, lane = t & 63;
    const int n0 = *n0p;
    const float nr = normP[row];

    // sum the 8 K-split partials for my 4 slots
    float4 dv = make_float4(0.f, 0.f, 0.f, 0.f);
    #pragma unroll
    for (int z = 0; z < 8; z++) {
        float4 p = *(const float4*)&dotPart[((size_t)z << 20) + (size_t)row * N_TOT + 4 * t];
        dv.x += p.x; dv.y += p.y; dv.z += p.z; dv.w += p.w;
    }

    // coarse cosines for my 4 compacted slots
    float cv[4];
    #pragma unroll
    for (int e = 0; e < 4; e++) {
        int s = 4 * t + e;
        int gj = colidx[s];
        float nb = (s < n0) ? normK[gj] : normP[gj];
        float d  = (e == 0) ? dv.x : (e == 1) ? dv.y : (e == 2) ? dv.z : dv.w;
        cv[e] = d * rsqrtf(nr * nb);
    }

    int   candZ[2][8];
    float cvalZ[2][8];
    bool  need[2];

    #pragma unroll
    for (int zz = 0; zz < 2; zz++) {
        float mv[4];
        #pragma unroll
        for (int e = 0; e < 4; e++) {
            int s = 4 * t + e;
            bool inz = zz ? (s >= n0) : (s < n0);
            mv[e] = inz ? cv[e] : -INFINITY;
        }
        #pragma unroll
        for (int it = 0; it < 8; it++) {
            float bv = mv[0]; int bj = 4 * t;
            #pragma unroll
            for (int e = 1; e < 4; e++) {
                int j = 4 * t + e;
                if (mv[e] > bv || (mv[e] == bv && j < bj)) { bv = mv[e]; bj = j; }
            }
            #pragma unroll
            for (int off = 32; off > 0; off >>= 1) {
                float ov = __shfl_xor(bv, off);
                int   oj = __shfl_xor(bj, off);
                if (ov > bv || (ov == bv && oj < bj)) { bv = ov; bj = oj; }
            }
            if (lane == 0) { s_bv[wave] = bv; s_bj[wave] = bj; }
            __syncthreads();
            float wv = s_bv[0]; int wj = s_bj[0];
            #pragma unroll
            for (int w = 1; w < 4; w++)
                if (s_bv[w] > wv || (s_bv[w] == wv && s_bj[w] < wj)) { wv = s_bv[w]; wj = s_bj[w]; }
            candZ[zz][it] = wj; cvalZ[zz][it] = wv;
            #pragma unroll
            for (int e = 0; e < 4; e++)
                if (wj == 4 * t + e) mv[e] = -INFINITY;
            __syncthreads();
        }
        const bool trust = (cvalZ[zz][0] - cvalZ[zz][1] > T_MARGIN) &&
                           (cvalZ[zz][1] - cvalZ[zz][2] > T_MARGIN);
        need[zz] = !trust;
        if (trust && t == 0) {
            int base = (zz * N_TOT + row) * 2;
            w01[base]     = cvalZ[zz][0];
            w01[base + 1] = cvalZ[zz][1];
            i01[base]     = colidx[candZ[zz][0]];
            i01[base + 1] = colidx[candZ[zz][1]];
        }
    }

    if (!need[0] && !need[1]) return;

    // reconstruct A row once (shared by both refines)
    {
        const unsigned short* Ah = Phi + (size_t)row * C_DIM;
        const char*           Al = Plo + (size_t)row * C_DIM;
        #pragma unroll
        for (int s = 0; s < 2; s++) {
            int c = t * 16 + s * 8;
            ushort8 hb = *(const ushort8*)&Ah[c];
            schar8  lb = *(const schar8*)&Al[c];
            #pragma unroll
            for (int e = 0; e < 8; e++) sAf[c + e] = h2f(hb[e]) + lo_dec(lb[e], hb[e]);
        }
    }
    __syncthreads();

    #pragma unroll
    for (int zz = 0; zz < 2; zz++) {
        if (!need[zz]) continue;
        const int grp = t >> 5, l32 = t & 31;
        const int cs  = candZ[zz][grp];
        const int gj  = colidx[cs];
        const unsigned short* bh_row = ((cs < n0) ? Khi : Phi) + (size_t)gj * C_DIM;
        const char*           bl_row = ((cs < n0) ? Klo : Plo) + (size_t)gj * C_DIM;
        float acc = 0.0f;
        for (int it = 0; it < 16; it++) {
            int c = it * 256 + l32 * 8;
            ushort8 hb = *(const ushort8*)&bh_row[c];
            schar8  lb = *(const schar8*)&bl_row[c];
            #pragma unroll
            for (int e = 0; e < 8; e++)
                acc = fmaf(sAf[c + e], h2f(hb[e]) + lo_dec(lb[e], hb[e]), acc);
        }
        #pragma unroll
        for (int off = 16; off > 0; off >>= 1) acc += __shfl_xor(acc, off);
        if (l32 == 0) s_rcv[grp] = acc;
        __syncthreads();

        if (t == 0) {
            float v1 = -INFINITY, v2 = -INFINITY;
            int   j1 = 0x7FFFFFFF, j2 = 0x7FFFFFFF;
            #pragma unroll
            for (int q = 0; q < 8; q++) {
                if (!(cvalZ[zz][q] > -1e29f)) continue;
                int s = candZ[zz][q];
                int gjx = colidx[s];
                float nb = (s < n0) ? normK[gjx] : normP[gjx];
                float cvx = s_rcv[q] * rsqrtf(nr * nb);
                int j = gjx;
                if (cvx > v1 || (cvx == v1 && j < j1)) {
                    v2 = v1; j2 = j1; v1 = cvx; j1 = j;
                } else if (cvx > v2 || (cvx == v2 && j < j2)) {
                    v2 = cvx; j2 = j;
                }
            }
            int base = (zz * N_TOT + row) * 2;
            w01[base]     = v1;
            w01[base + 1] = v2;
            i01[base]     = j1;
            i01[base + 1] = j2;
        }
        __syncthreads();
    }
}

// ---------------------------------------------------------------------------
// output: inline means->softmax->weights, copy generated & known (float4),
// rtn = weighted gather. grid (4096), block 256.
__global__ __launch_bounds__(256) void output_kernel(const float* __restrict__ G,
                                                     const float* __restrict__ Kn,
                                                     const float* __restrict__ flag,
                                                     const float* __restrict__ w01,
                                                     const int* __restrict__ i01,
                                                     float* __restrict__ out) {
    __shared__ float red[5][4];
    __shared__ float wts[4];
    const int c  = blockIdx.x;
    const int t  = threadIdx.x;
    const int n4 = t * 4;

    float4 fv = *(const float4*)&flag[n4];
    const float fa[4] = {fv.x, fv.y, fv.z, fv.w};

    float pm[5] = {};
    #pragma unroll
    for (int e = 0; e < 4; e++) {
        int n = n4 + e;
        float m = fa[e];
        pm[0] += m;
        pm[1] += m * w01[n * 2 + 0];
        pm[2] += m * w01[n * 2 + 1];
        pm[3] += m * w01[2 * N_TOT + n * 2 + 0];
        pm[4] += m * w01[2 * N_TOT + n * 2 + 1];
    }
    #pragma unroll
    for (int i = 0; i < 5; i++)
        #pragma unroll
        for (int off = 32; off > 0; off >>= 1)
            pm[i] += __shfl_xor(pm[i], off);
    const int wave = t >> 6, lane = t & 63;
    if (lane == 0) {
        #pragma unroll
        for (int i = 0; i < 5; i++) red[i][wave] = pm[i];
    }
    __syncthreads();
    if (t == 0) {
        float tot[5];
        #pragma unroll
        for (int i = 0; i < 5; i++)
            tot[i] = red[i][0] + red[i][1] + red[i][2] + red[i][3];
        float inv = 1.0f / tot[0];
        float mv[4] = {tot[1] * inv, tot[2] * inv, tot[3] * inv, tot[4] * inv};
        float mx = fmaxf(fmaxf(mv[0], mv[1]), fmaxf(mv[2], mv[3]));
        float e[4], s = 0.0f;
        #pragma unroll
        for (int q = 0; q < 4; q++) { e[q] = expf(mv[q] - mx); s += e[q]; }
        #pragma unroll
        for (int q = 0; q < 4; q++) wts[q] = e[q] / s;
    }
    __syncthreads();
    const float w0 = wts[0], w1 = wts[1], w2 = wts[2], w3 = wts[3];

    float4 gv = *(const float4*)&G[c * N_TOT + n4];
    float4 kv = *(const float4*)&Kn[c * N_TOT + n4];
    *(float4*)&out[c * N_TOT + n4] = gv;
    *(float4*)&out[C_DIM * N_TOT + c * N_TOT + n4] = kv;

    float val[4];
    #pragma unroll
    for (int e = 0; e < 4; e++) {
        int n = n4 + e;
        float v = 0.0f;
        if (fa[e] == 1.0f) {
            int c00 = i01[n * 2 + 0];
            int c01 = i01[n * 2 + 1];
            int c10 = i01[2 * N_TOT + n * 2 + 0];
            int c11 = i01[2 * N_TOT + n * 2 + 1];
            v = w0 * Kn[c * N_TOT + c00] + w1 * Kn[c * N_TOT + c01]
              + w2 * G[c * N_TOT + c10]  + w3 * G[c * N_TOT + c11];
        }
        if (n == 0) {
            bool m0 = (flag[0] == 1.0f);
            int c00 = i01[0], c01 = i01[1];
            int c10 = i01[2 * N_TOT], c11 = i01[2 * N_TOT + 1];
            float kn0 = Kn[c * N_TOT];
            float g0  = G[c * N_TOT];
            if (!(m0 && c00 == 0)) v += w0 * kn0;
            if (!(m0 && c01 == 0)) v += w1 * kn0;
            if (!(m0 && c10 == 0)) v += w2 * g0;
            if (!(m0 && c11 == 0)) v += w3 * g0;
        }
        val[e] = v;
    }
    *(float4*)&out[2 * C_DIM * N_TOT + c * N_TOT + n4] =
        make_float4(val[0], val[1], val[2], val[3]);
}

// ---------------------------------------------------------------------------
extern "C" void kernel_launch(void* const* d_in, const int* in_sizes, int n_in,
                              void* d_out, int out_size, void* d_ws, size_t ws_size,
                              hipStream_t stream) {
    const float* G    = (const float*)d_in[0];
    const float* Kn   = (const float*)d_in[1];
    const float* flag = (const float*)d_in[2];
    float* out = (float*)d_out;

    // ws layout (~56 MB; the harness poisons the whole fixed ws allocation
    // regardless, so ws growth is free)
    char* p = (char*)d_ws;
    unsigned short* Phi = (unsigned short*)p;  p += (size_t)N_TOT * C_DIM * 2;  // 8 MB
    unsigned short* Khi = (unsigned short*)p;  p += (size_t)N_TOT * C_DIM * 2;  // 8 MB
    char* Plo = p;                             p += (size_t)N_TOT * C_DIM;      // 4 MB
    char* Klo = p;                             p += (size_t)N_TOT * C_DIM;      // 4 MB
    float* dotPart = (float*)p;                p += (size_t)8 * N_TOT * N_TOT * 4; // 32 MB
    float* normP  = (float*)p;                 p += N_TOT * 4;
    float* normK  = (float*)p;                 p += N_TOT * 4;
    float* w01    = (float*)p;                 p += 4 * N_TOT * 4;
    int*   i01    = (int*)p;                   p += 4 * N_TOT * 4;
    int*   colidx = (int*)p;                   p += N_TOT * 4;
    int*   n0p    = (int*)p;

    // zero only the atomically-accumulated norms (8 KB)
    hipMemsetAsync(normP, 0, 2 * N_TOT * sizeof(float), stream);

    split_norms<<<dim3(64, 16, 2), 256, 0, stream>>>(G, Kn, flag, Phi, Plo, Khi, Klo,
                                                     normP, normK, colidx, n0p);
    gemm_coarse<<<dim3(16, 8, 8), 256, 0, stream>>>(Phi, Khi, colidx, n0p, dotPart);
    topk_refine<<<1024, 256, 0, stream>>>(dotPart, Phi, Plo, Khi, Klo,
                                          normP, normK, colidx, n0p, w01, i01);
    output_kernel<<<4096, 256, 0, stream>>>(G, Kn, flag, w01, i01, out);
}